// Round 18
// baseline (53.627 us; speedup 1.0000x reference)
//
#include <hip/hip_runtime.h>
#include <cstddef>

#define HOP 256
#define NSTFT 513
#define N_MELS 80
#define T_AUDIO 320000
#define NUM_FRAMES 1251
#define NBATCH 16
#define TOTAL_FRAMES (NBATCH * NUM_FRAMES)  // 20016 = 1251 blocks * 4 waves * 4 frames

// Slaney mel constants
#define LOGSTEP 0.06875177742094913f
#define MEL_MAX 45.24564047f
#define DF 15.625f

__device__ __forceinline__ int reflect_idx(int j) {
    j = (j < 0) ? -j : j;
    j = (j >= T_AUDIO) ? (2 * T_AUDIO - 2 - j) : j;
    return j;
}

// mel band index of bin k (self-consistent with weight table build)
__device__ __forceinline__ int m1_of(int k) {
    const float f = k * DF;
    const float mel = (f < 1000.f) ? (3.0f / 200.0f) * f
                                   : 15.0f + logf(f * 1e-3f) * (1.0f / LOGSTEP);
    return (int)floorf(mel * (81.0f / MEL_MAX));
}

__device__ __forceinline__ int swz(int k) {  // conflict-breaking LDS slot
    return (k & ~15) | ((k ^ (k >> 4)) & 15);
}

// pack two f32 -> 2xbf16 (dst[15:0]=lo, dst[31:16]=hi)
__device__ __forceinline__ unsigned cvt_pk_bf16(float lo, float hi) {
    unsigned r;
    asm("v_cvt_pk_bf16_f32 %0, %1, %2" : "=v"(r) : "v"(lo), "v"(hi));
    return r;
}
__device__ __forceinline__ float lo16f(unsigned u) { return __uint_as_float(u << 16); }
__device__ __forceinline__ float hi16f(unsigned u) { return __uint_as_float(u & 0xffff0000u); }

// ---- semantics-robust permlane sums: s = v + v[lane^half] ----
__device__ __forceinline__ float plsum32(float v) {
#if __has_builtin(__builtin_amdgcn_permlane32_swap)
    auto r = __builtin_amdgcn_permlane32_swap(__float_as_int(v), __float_as_int(v), false, false);
    return __int_as_float(r[0]) + __int_as_float(r[1]);
#else
    return v + __shfl_xor(v, 32);
#endif
}
__device__ __forceinline__ float plsum16(float v) {
#if __has_builtin(__builtin_amdgcn_permlane16_swap)
    auto r = __builtin_amdgcn_permlane16_swap(__float_as_int(v), __float_as_int(v), false, false);
    return __int_as_float(r[0]) + __int_as_float(r[1]);
#else
    return v + __shfl_xor(v, 16);
#endif
}

// DPP cross-lane exchange (VALU pipe) for xor 1/2/8
#define DPP_XOR1 0xB1   // quad_perm [1,0,3,2]
#define DPP_XOR2 0x4E   // quad_perm [2,3,0,1]
#define DPP_XOR8 0x128  // row_ror:8
template<int CTRL>
__device__ __forceinline__ float dppf(float x) {
    return __int_as_float(__builtin_amdgcn_update_dpp(
        0, __float_as_int(x), CTRL, 0xF, 0xF, true));
}

template<class F>
__device__ __forceinline__ void cstage(float (&zr)[2][16], float (&zi)[2][16],
                                       float sg, float twr_, float twi_, F comm) {
    #pragma unroll
    for (int p = 0; p < 2; ++p) {
        #pragma unroll
        for (int r = 0; r < 16; ++r) {
            const float pr  = comm(zr[p][r]);
            const float pim = comm(zi[p][r]);
            const float qr = fmaf(sg, zr[p][r], pr);
            const float qi = fmaf(sg, zi[p][r], pim);
            zr[p][r] = fmaf(qr, twr_, -(qi * twi_));
            zi[p][r] = fmaf(qr, twi_, qi * twr_);
        }
    }
}

template<class FS>
__device__ __forceinline__ void cstage_sum(float (&zr)[2][16], float (&zi)[2][16],
                                           float m2, float twr_, float twi_, FS sumf) {
    #pragma unroll
    for (int p = 0; p < 2; ++p) {
        #pragma unroll
        for (int r = 0; r < 16; ++r) {
            const float sR = sumf(zr[p][r]);
            const float sI = sumf(zi[p][r]);
            const float qr = fmaf(m2, zr[p][r], sR);
            const float qi = fmaf(m2, zi[p][r], sI);
            zr[p][r] = fmaf(qr, twr_, -(qi * twi_));
            zi[p][r] = fmaf(qr, twi_, qi * twr_);
        }
    }
}

// Self-contained: 4 waves/block, 4 frames/wave (2 real-packed complex FFTs).
// Four-step 1024-pt FFT (16 regs x 64 lanes); xor32/16 on VALU (permlane),
// xor8/2 via DPP cstage, xor4 via DS shfl, xor1 via DPP BARE butterfly
// (twiddle is identity on every lane: jj = (lane&0)<<9 = 0). Work-split
// separation (lane pair computes disjoint halves, one shfl exchange; mags
// bitwise-equal to full compute). Packed bf16x4 smag -> single mel pass,
// split up/down-slope weight loops (0.5 folded into weights). Single-sync
// table build. R15 structure otherwise verbatim (VGPR 76 / 6 waves/SIMD).
__global__ __launch_bounds__(256) void melspec_pk10_kernel(
    const float* __restrict__ wav,     // 16 x 320000
    const float* __restrict__ window,  // 1024
    const float* __restrict__ fb,      // 513 x 80
    const float* __restrict__ cosT,    // 1024 x 513 (row1 = cos(2pi j/1024))
    const float* __restrict__ sinT,    // 1024 x 513 (row1 = -sin(2pi j/1024))
    float* __restrict__ out)           // 16 x 80 x 1251
{
    __shared__ uint2  smag4[4][512];       // 16 KB: 4xbf16 mags (A0,B0 | A1,B1)
    __shared__ float  swu[512];            // 2 KB up-slope weights (0.5-scaled, swizzled)
    __shared__ float  swd[512];            // 2 KB down-slope weights
    __shared__ unsigned short ks_l[84];    // band boundaries

    const int tid = threadIdx.x;
    const int lane = tid & 63;
    const int w = tid >> 6;
    const int g0 = (blockIdx.x * 4 + w) * 4;

    const int BREV4[16] = {0,8,4,12,2,10,6,14,1,9,5,13,3,11,7,15};
    const int SIG[16]   = {0,1,3,2,7,6,5,4,15,14,13,12,11,10,9,8};
    const float W16R[8] = {1.0f, 0.92387953251128674f, 0.70710678118654752f, 0.38268343236508977f,
                           0.0f, -0.38268343236508977f, -0.70710678118654752f, -0.92387953251128674f};
    const float W16I[8] = {0.0f, -0.38268343236508977f, -0.70710678118654752f, -0.92387953251128674f,
                           -1.0f, -0.92387953251128674f, -0.70710678118654752f, -0.38268343236508977f};

    // ---- per-block table build (single sync, R12-style) ----
    if (tid == 0) { ks_l[81] = 512; ks_l[82] = 512; ks_l[83] = 512; }
    for (int k = tid; k <= 512; k += 256) {
        const int mc = m1_of(k);
        if (k <= 511) {
            swu[swz(k)] = (mc >= 0 && mc <= 79) ? 0.5f * fb[k * N_MELS + mc] : 0.0f;
            swd[swz(k)] = (mc >= 1 && mc <= 80) ? 0.5f * fb[k * N_MELS + mc - 1] : 0.0f;
        }
        if (k >= 1) {
            const int mp = m1_of(k - 1);
            for (int m = mp + 1; m <= mc; ++m) ks_l[m] = (unsigned short)k;
            if (k == 1) ks_l[0] = 1;
        }
    }
    __syncthreads();

    unsigned bf0, ff0, bf3;
    {
        const unsigned g = (unsigned)g0;
        bf0 = g / NUM_FRAMES; ff0 = g - bf0 * NUM_FRAMES;
        bf3 = (unsigned)(g0 + 3) / NUM_FRAMES;
    }

    // ---- window ----
    float win[16];
    #pragma unroll
    for (int r = 0; r < 16; ++r) win[r] = window[r * 64 + lane];

    // ---- load 4 frames (75%-overlap shared-chunk; interior fast path) ----
    float zr[2][16], zi[2][16];
    if (bf0 == bf3) {
        const float* wb = wav + (size_t)bf0 * T_AUDIO;
        const int base = (int)ff0 * HOP - 512;
        float ch[28];
        if (base >= 0 && base + 27 * 64 + 63 < T_AUDIO) {
            #pragma unroll
            for (int c = 0; c < 28; ++c)
                ch[c] = wb[base + c * 64 + lane];
        } else {
            #pragma unroll
            for (int c = 0; c < 28; ++c)
                ch[c] = wb[reflect_idx(base + c * 64 + lane)];
        }
        #pragma unroll
        for (int r = 0; r < 16; ++r) {
            zr[0][r] = ch[r]      * win[r];
            zi[0][r] = ch[r + 4]  * win[r];
            zr[1][r] = ch[r + 8]  * win[r];
            zi[1][r] = ch[r + 12] * win[r];
        }
    } else {
        #pragma unroll
        for (int fi = 0; fi < 4; ++fi) {
            const unsigned g = (unsigned)(g0 + fi);
            const unsigned bb = g / NUM_FRAMES;
            const unsigned ffr = g - bb * NUM_FRAMES;
            const float* wb = wav + (size_t)bb * T_AUDIO;
            const int base = (int)ffr * HOP - 512;
            #pragma unroll
            for (int r = 0; r < 16; ++r) {
                const float v = wb[reflect_idx(base + r * 64 + lane)] * win[r];
                if (fi == 0) zr[0][r] = v;
                else if (fi == 1) zi[0][r] = v;
                else if (fi == 2) zr[1][r] = v;
                else zi[1][r] = v;
            }
        }
    }

    const float* twc = cosT + NSTFT;  // row n=1
    const float* tws = sinT + NSTFT;

    // ---- cross twiddles: wk[k] = W_1024^(lane*k) via complex powers ----
    const float w1r = twc[lane];
    const float w1i = tws[lane];
    float wkr[16], wki[16];
    wkr[0] = 1.0f; wki[0] = 0.0f;
    #pragma unroll
    for (int k = 1; k < 16; ++k) {
        wkr[k] = wkr[k-1] * w1r - wki[k-1] * w1i;
        wki[k] = wkr[k-1] * w1i + wki[k-1] * w1r;
    }

    // ---- stage twiddles for cross-lane FFT (stages 0..4; stage 5 is identity) ----
    float c64[5], s64[5];
    #pragma unroll
    for (int t = 0; t < 5; ++t) {
        const int half = 32 >> t;
        const bool hi = (lane & half) != 0;
        const int jj = (lane & (half - 1)) << (t + 4);
        c64[t] = hi ? twc[jj] : 1.0f;
        s64[t] = hi ? tws[jj] : 0.0f;
    }

    // ---- A) 16-pt DIF FFT in registers ----
    #define CBFLY(ar, ai, br, bi, wr, wi) { \
        const float _tr = (ar) - (br), _ti = (ai) - (bi); \
        (ar) += (br); (ai) += (bi); \
        (br) = _tr * (wr) - _ti * (wi); \
        (bi) = _tr * (wi) + _ti * (wr); }

    #pragma unroll
    for (int p = 0; p < 2; ++p) {
        #pragma unroll
        for (int q = 0; q < 8; ++q) CBFLY(zr[p][q], zi[p][q], zr[p][q+8], zi[p][q+8], W16R[q], W16I[q]);
        #pragma unroll
        for (int g = 0; g < 16; g += 8)
            #pragma unroll
            for (int q = 0; q < 4; ++q) CBFLY(zr[p][g+q], zi[p][g+q], zr[p][g+q+4], zi[p][g+q+4], W16R[2*q], W16I[2*q]);
        #pragma unroll
        for (int g = 0; g < 16; g += 4)
            #pragma unroll
            for (int q = 0; q < 2; ++q) CBFLY(zr[p][g+q], zi[p][g+q], zr[p][g+q+2], zi[p][g+q+2], W16R[4*q], W16I[4*q]);
        #pragma unroll
        for (int g = 0; g < 16; g += 2) CBFLY(zr[p][g], zi[p][g], zr[p][g+1], zi[p][g+1], 1.0f, 0.0f);
    }

    // ---- B) cross twiddle ----
    #pragma unroll
    for (int r = 1; r < 16; ++r) {
        const float c1 = wkr[BREV4[r]];
        const float s1 = wki[BREV4[r]];
        #pragma unroll
        for (int p = 0; p < 2; ++p) {
            const float xr = zr[p][r], xi = zi[p][r];
            zr[p][r] = xr * c1 - xi * s1;
            zi[p][r] = xr * s1 + xi * c1;
        }
    }

    // ---- C) 64-pt DIF FFT across lanes ----
    {
        cstage_sum(zr, zi, (lane & 32) ? -2.0f : 0.0f, c64[0], s64[0],
                   [](float v) { return plsum32(v); });
        cstage_sum(zr, zi, (lane & 16) ? -2.0f : 0.0f, c64[1], s64[1],
                   [](float v) { return plsum16(v); });
        float sg;
        sg = (lane & 8) ? -1.0f : 1.0f;
        cstage(zr, zi, sg, c64[2], s64[2], [](float v) { return dppf<DPP_XOR8>(v); });
        sg = (lane & 4) ? -1.0f : 1.0f;
        cstage(zr, zi, sg, c64[3], s64[3], [](float v) { return __shfl_xor(v, 4); });
        sg = (lane & 2) ? -1.0f : 1.0f;
        cstage(zr, zi, sg, c64[4], s64[4], [](float v) { return dppf<DPP_XOR2>(v); });
        // t=5 (xor1): twiddle = W^0 = 1 for ALL lanes: bare sum/diff butterfly
        {
            const float sg5 = (lane & 1) ? -1.0f : 1.0f;
            #pragma unroll
            for (int p = 0; p < 2; ++p) {
                #pragma unroll
                for (int r = 0; r < 16; ++r) {
                    zr[p][r] = fmaf(sg5, zr[p][r], dppf<DPP_XOR1>(zr[p][r]));
                    zi[p][r] = fmaf(sg5, zi[p][r], dppf<DPP_XOR1>(zi[p][r]));
                }
            }
        }
    }

    // ---- separation + magnitude -> packed bf16x4 smag (work split across lane pair) ----
    // Hi lane computes from its reg SIG[r] (bin 1024-klo, mirror of klo); partner
    // operand from lo lane's reg r. Each lane sends what its partner needs:
    // lo sends z1[r], hi sends z0[SIG[r]]. Bitwise equal to the full computation.
    const int k2 = (int)(__brev((unsigned)lane) >> 26);
    const int lp0 = (int)(__brev((unsigned)((64 - k2) & 63)) >> 26);
    const bool hasbin = (k2 < 32);
    #pragma unroll
    for (int r = 1; r < 16; ++r) {
        const float sxr = hasbin ? zr[1][r] : zr[0][SIG[r]];
        const float sxi = hasbin ? zi[1][r] : zi[0][SIG[r]];
        const float cx = __shfl_xor(sxr, 63);
        const float cy = __shfl_xor(sxi, 63);
        const float a = hasbin ? zr[0][r] : zr[1][SIG[r]];
        const float b = hasbin ? zi[0][r] : zi[1][SIG[r]];
        const float sA = a + cx, dA = b - cy;
        const float sB = b + cy, dB = a - cx;
        const float magA = sqrtf(sA * sA + dA * dA);
        const float magB = sqrtf(sB * sB + dB * dB);
        const unsigned pk = cvt_pk_bf16(magA, magB);
        const unsigned pko = (unsigned)__shfl_xor((int)pk, 63);
        if (hasbin) {
            const int k1 = BREV4[r];
            const int k = k2 * 16 + k1;
            smag4[w][(k & ~15) | (k1 ^ (k2 & 15))] = make_uint2(pk, pko);
        }
    }
    {   // r == 0: bins are multiples of 16; partner via lp0 broadcast
        const float cx0 = __shfl(zr[0][0], lp0), cy0 = __shfl(zi[0][0], lp0);
        const float cx1 = __shfl(zr[1][0], lp0), cy1 = __shfl(zi[1][0], lp0);
        if (hasbin) {
            const float a0 = zr[0][0], b0 = zi[0][0];
            const float mA0 = sqrtf((a0 + cx0) * (a0 + cx0) + (b0 - cy0) * (b0 - cy0));
            const float mB0 = sqrtf((b0 + cy0) * (b0 + cy0) + (a0 - cx0) * (a0 - cx0));
            const float a1 = zr[1][0], b1 = zi[1][0];
            const float mA1 = sqrtf((a1 + cx1) * (a1 + cx1) + (b1 - cy1) * (b1 - cy1));
            const float mB1 = sqrtf((b1 + cy1) * (b1 + cy1) + (a1 - cx1) * (a1 - cx1));
            const int k = k2 * 16;
            smag4[w][(k & ~15) | (0 ^ (k2 & 15))] =
                make_uint2(cvt_pk_bf16(mA0, mB0), cvt_pk_bf16(mA1, mB1));
        }
    }

    // ---- mel: 160 tasks = (m, half-triangle), 4 frames/task, split up/down loops ----
    #pragma unroll
    for (int ii = 0; ii < 3; ++ii) {
        const int t2 = lane + 64 * ii;
        if (t2 < 2 * N_MELS) {
            const int m = 79 - (t2 >> 1);      // descending width order
            const int half = t2 & 1;
            const int ka = ks_l[m], kb = ks_l[m + 1], kc = ks_l[m + 2];
            const int km = (ka + kc + 1) >> 1;
            const int kbeg = half ? km : ka;
            const int kend = half ? kc : km;
            float a0 = 0.f, b0 = 0.f, a1 = 0.f, b1 = 0.f;
            const int upend = min(kb, kend);
            for (int k = kbeg; k < upend; ++k) {
                const int sl = swz(k);
                const uint2 mg = smag4[w][sl];
                const float ws = swu[sl];
                a0 = fmaf(lo16f(mg.x), ws, a0);
                b0 = fmaf(hi16f(mg.x), ws, b0);
                a1 = fmaf(lo16f(mg.y), ws, a1);
                b1 = fmaf(hi16f(mg.y), ws, b1);
            }
            const int dnbeg = max(kb, kbeg);
            for (int k = dnbeg; k < kend; ++k) {
                const int sl = swz(k);
                const uint2 mg = smag4[w][sl];
                const float ws = swd[sl];
                a0 = fmaf(lo16f(mg.x), ws, a0);
                b0 = fmaf(hi16f(mg.x), ws, b0);
                a1 = fmaf(lo16f(mg.y), ws, a1);
                b1 = fmaf(hi16f(mg.y), ws, b1);
            }
            a0 += dppf<DPP_XOR1>(a0);  b0 += dppf<DPP_XOR1>(b0);
            a1 += dppf<DPP_XOR1>(a1);  b1 += dppf<DPP_XOR1>(b1);
            const float v0 = half ? b0 : a0;
            const float v1 = half ? b1 : a1;
            const unsigned gA = (unsigned)(g0 + half);
            const unsigned bbA = gA / NUM_FRAMES;
            const unsigned ffA = gA - bbA * NUM_FRAMES;
            out[((size_t)bbA * N_MELS + m) * NUM_FRAMES + ffA] = v0;
            const unsigned gB = (unsigned)(g0 + 2 + half);
            const unsigned bbB = gB / NUM_FRAMES;
            const unsigned ffB = gB - bbB * NUM_FRAMES;
            out[((size_t)bbB * N_MELS + m) * NUM_FRAMES + ffB] = v1;
        }
    }
}

extern "C" void kernel_launch(void* const* d_in, const int* in_sizes, int n_in,
                              void* d_out, int out_size, void* d_ws, size_t ws_size,
                              hipStream_t stream) {
    const float* wav    = (const float*)d_in[0];
    const float* window = (const float*)d_in[1];
    const float* fb     = (const float*)d_in[2];
    const float* cosT   = (const float*)d_in[3];
    const float* sinT   = (const float*)d_in[4];
    float* out = (float*)d_out;

    const int blocks = TOTAL_FRAMES / 16;  // 1251: 4 waves/block, 4 frames/wave
    melspec_pk10_kernel<<<blocks, 256, 0, stream>>>(wav, window, fb, cosT, sinT, out);
}

// Round 19
// 45.887 us; speedup vs baseline: 1.1687x; 1.1687x over previous
//
#include <hip/hip_runtime.h>
#include <cstddef>

#define HOP 256
#define NSTFT 513
#define N_MELS 80
#define T_AUDIO 320000
#define NUM_FRAMES 1251
#define NBATCH 16
#define TOTAL_FRAMES (NBATCH * NUM_FRAMES)  // 20016 = 1251 blocks * 4 waves * 4 frames

// Slaney mel constants
#define LOGSTEP 0.06875177742094913f
#define MEL_MAX 45.24564047f
#define DF 15.625f

__device__ __forceinline__ int reflect_idx(int j) {
    j = (j < 0) ? -j : j;
    j = (j >= T_AUDIO) ? (2 * T_AUDIO - 2 - j) : j;
    return j;
}

// mel band index of bin k (self-consistent with weight table build)
__device__ __forceinline__ int m1_of(int k) {
    const float f = k * DF;
    const float mel = (f < 1000.f) ? (3.0f / 200.0f) * f
                                   : 15.0f + logf(f * 1e-3f) * (1.0f / LOGSTEP);
    return (int)floorf(mel * (81.0f / MEL_MAX));
}

__device__ __forceinline__ int swz(int k) {  // conflict-breaking LDS slot
    return (k & ~15) | ((k ^ (k >> 4)) & 15);
}

// pack two f32 -> 2xbf16 (dst[15:0]=lo, dst[31:16]=hi)
__device__ __forceinline__ unsigned cvt_pk_bf16(float lo, float hi) {
    unsigned r;
    asm("v_cvt_pk_bf16_f32 %0, %1, %2" : "=v"(r) : "v"(lo), "v"(hi));
    return r;
}
__device__ __forceinline__ float lo16f(unsigned u) { return __uint_as_float(u << 16); }
__device__ __forceinline__ float hi16f(unsigned u) { return __uint_as_float(u & 0xffff0000u); }

// ---- semantics-robust permlane sums: s = v + v[lane^half] ----
__device__ __forceinline__ float plsum32(float v) {
#if __has_builtin(__builtin_amdgcn_permlane32_swap)
    auto r = __builtin_amdgcn_permlane32_swap(__float_as_int(v), __float_as_int(v), false, false);
    return __int_as_float(r[0]) + __int_as_float(r[1]);
#else
    return v + __shfl_xor(v, 32);
#endif
}
__device__ __forceinline__ float plsum16(float v) {
#if __has_builtin(__builtin_amdgcn_permlane16_swap)
    auto r = __builtin_amdgcn_permlane16_swap(__float_as_int(v), __float_as_int(v), false, false);
    return __int_as_float(r[0]) + __int_as_float(r[1]);
#else
    return v + __shfl_xor(v, 16);
#endif
}

// DPP cross-lane exchange (VALU pipe) for xor 1/2/8
#define DPP_XOR1 0xB1   // quad_perm [1,0,3,2]
#define DPP_XOR2 0x4E   // quad_perm [2,3,0,1]
#define DPP_XOR8 0x128  // row_ror:8
template<int CTRL>
__device__ __forceinline__ float dppf(float x) {
    return __int_as_float(__builtin_amdgcn_update_dpp(
        0, __float_as_int(x), CTRL, 0xF, 0xF, true));
}

template<class F>
__device__ __forceinline__ void cstage(float (&zr)[2][16], float (&zi)[2][16],
                                       float sg, float twr_, float twi_, F comm) {
    #pragma unroll
    for (int p = 0; p < 2; ++p) {
        #pragma unroll
        for (int r = 0; r < 16; ++r) {
            const float pr  = comm(zr[p][r]);
            const float pim = comm(zi[p][r]);
            const float qr = fmaf(sg, zr[p][r], pr);
            const float qi = fmaf(sg, zi[p][r], pim);
            zr[p][r] = fmaf(qr, twr_, -(qi * twi_));
            zi[p][r] = fmaf(qr, twi_, qi * twr_);
        }
    }
}

template<class FS>
__device__ __forceinline__ void cstage_sum(float (&zr)[2][16], float (&zi)[2][16],
                                           float m2, float twr_, float twi_, FS sumf) {
    #pragma unroll
    for (int p = 0; p < 2; ++p) {
        #pragma unroll
        for (int r = 0; r < 16; ++r) {
            const float sR = sumf(zr[p][r]);
            const float sI = sumf(zi[p][r]);
            const float qr = fmaf(m2, zr[p][r], sR);
            const float qi = fmaf(m2, zi[p][r], sI);
            zr[p][r] = fmaf(qr, twr_, -(qi * twi_));
            zi[p][r] = fmaf(qr, twi_, qi * twr_);
        }
    }
}

// Self-contained: 4 waves/block, 4 frames/wave (2 real-packed complex FFTs).
// Four-step 1024-pt FFT (16 regs x 64 lanes); xor32/16 on VALU (permlane),
// xor8/2/1 via DPP, xor4 via DS. Work-split separation (lane pair computes
// disjoint halves, one shfl exchange; mags bitwise-equal to full compute).
// Packed bf16x4 smag -> single mel pass, split up/down-slope weight loops
// (0.5 folded into weights). Table build per block with mtab LDS pass
// (one m1_of eval per k). No setup kernel, no workspace.
// NOTE (R17/R18 lesson): do NOT specialize the xor1/xor2 FFT stages into
// sum/diff or select-rotate forms — both variants inflate VGPR 76->100
// (regalloc over the 64-element unrolled region) and cost ~+6us via the
// occupancy cliff, despite saving VALU instructions.
__global__ __launch_bounds__(256) void melspec_pk7_kernel(
    const float* __restrict__ wav,     // 16 x 320000
    const float* __restrict__ window,  // 1024
    const float* __restrict__ fb,      // 513 x 80
    const float* __restrict__ cosT,    // 1024 x 513 (row1 = cos(2pi j/1024))
    const float* __restrict__ sinT,    // 1024 x 513 (row1 = -sin(2pi j/1024))
    float* __restrict__ out)           // 16 x 80 x 1251
{
    __shared__ uint2  smag4[4][512];       // 16 KB: 4xbf16 mags (A0,B0 | A1,B1)
    __shared__ float  swu[512];            // 2 KB up-slope weights (0.5-scaled, swizzled)
    __shared__ float  swd[512];            // 2 KB down-slope weights
    __shared__ unsigned short ks_l[84];    // band boundaries
    __shared__ unsigned char  mtab[513];   // m1 per bin (build scratch)

    const int tid = threadIdx.x;
    const int lane = tid & 63;
    const int w = tid >> 6;
    const int g0 = (blockIdx.x * 4 + w) * 4;

    const int BREV4[16] = {0,8,4,12,2,10,6,14,1,9,5,13,3,11,7,15};
    const int SIG[16]   = {0,1,3,2,7,6,5,4,15,14,13,12,11,10,9,8};
    const float W16R[8] = {1.0f, 0.92387953251128674f, 0.70710678118654752f, 0.38268343236508977f,
                           0.0f, -0.38268343236508977f, -0.70710678118654752f, -0.92387953251128674f};
    const float W16I[8] = {0.0f, -0.38268343236508977f, -0.70710678118654752f, -0.92387953251128674f,
                           -1.0f, -0.92387953251128674f, -0.70710678118654752f, -0.38268343236508977f};

    // ---- per-block table build: one m1_of per k via mtab ----
    for (int k = tid; k <= 512; k += 256) mtab[k] = (unsigned char)m1_of(k);
    if (tid == 0) { ks_l[81] = 512; ks_l[82] = 512; ks_l[83] = 512; }
    __syncthreads();
    for (int k = tid; k <= 512; k += 256) {
        const int mc = mtab[k];
        if (k <= 511) {
            swu[swz(k)] = (mc <= 79) ? 0.5f * fb[k * N_MELS + mc] : 0.0f;
            swd[swz(k)] = (mc >= 1 && mc <= 80) ? 0.5f * fb[k * N_MELS + mc - 1] : 0.0f;
        }
        if (k >= 1) {
            const int mp = mtab[k - 1];
            for (int m = mp + 1; m <= mc; ++m) ks_l[m] = (unsigned short)k;
            if (k == 1) ks_l[0] = 1;
        }
    }
    __syncthreads();

    unsigned bf0, ff0, bf3;
    {
        const unsigned g = (unsigned)g0;
        bf0 = g / NUM_FRAMES; ff0 = g - bf0 * NUM_FRAMES;
        bf3 = (unsigned)(g0 + 3) / NUM_FRAMES;
    }

    // ---- window ----
    float win[16];
    #pragma unroll
    for (int r = 0; r < 16; ++r) win[r] = window[r * 64 + lane];

    // ---- load 4 frames (75%-overlap shared-chunk; interior fast path) ----
    float zr[2][16], zi[2][16];
    if (bf0 == bf3) {
        const float* wb = wav + (size_t)bf0 * T_AUDIO;
        const int base = (int)ff0 * HOP - 512;
        float ch[28];
        if (base >= 0 && base + 27 * 64 + 63 < T_AUDIO) {
            #pragma unroll
            for (int c = 0; c < 28; ++c)
                ch[c] = wb[base + c * 64 + lane];
        } else {
            #pragma unroll
            for (int c = 0; c < 28; ++c)
                ch[c] = wb[reflect_idx(base + c * 64 + lane)];
        }
        #pragma unroll
        for (int r = 0; r < 16; ++r) {
            zr[0][r] = ch[r]      * win[r];
            zi[0][r] = ch[r + 4]  * win[r];
            zr[1][r] = ch[r + 8]  * win[r];
            zi[1][r] = ch[r + 12] * win[r];
        }
    } else {
        #pragma unroll
        for (int fi = 0; fi < 4; ++fi) {
            const unsigned g = (unsigned)(g0 + fi);
            const unsigned bb = g / NUM_FRAMES;
            const unsigned ffr = g - bb * NUM_FRAMES;
            const float* wb = wav + (size_t)bb * T_AUDIO;
            const int base = (int)ffr * HOP - 512;
            #pragma unroll
            for (int r = 0; r < 16; ++r) {
                const float v = wb[reflect_idx(base + r * 64 + lane)] * win[r];
                if (fi == 0) zr[0][r] = v;
                else if (fi == 1) zi[0][r] = v;
                else if (fi == 2) zr[1][r] = v;
                else zi[1][r] = v;
            }
        }
    }

    const float* twc = cosT + NSTFT;  // row n=1
    const float* tws = sinT + NSTFT;

    // ---- cross twiddles: wk[k] = W_1024^(lane*k) via complex powers ----
    const float w1r = twc[lane];
    const float w1i = tws[lane];
    float wkr[16], wki[16];
    wkr[0] = 1.0f; wki[0] = 0.0f;
    #pragma unroll
    for (int k = 1; k < 16; ++k) {
        wkr[k] = wkr[k-1] * w1r - wki[k-1] * w1i;
        wki[k] = wkr[k-1] * w1i + wki[k-1] * w1r;
    }

    // ---- stage twiddles for cross-lane FFT ----
    float c64[6], s64[6];
    #pragma unroll
    for (int t = 0; t < 6; ++t) {
        const int half = 32 >> t;
        const bool hi = (lane & half) != 0;
        const int jj = (lane & (half - 1)) << (t + 4);
        c64[t] = hi ? twc[jj] : 1.0f;
        s64[t] = hi ? tws[jj] : 0.0f;
    }

    // ---- A) 16-pt DIF FFT in registers ----
    #define CBFLY(ar, ai, br, bi, wr, wi) { \
        const float _tr = (ar) - (br), _ti = (ai) - (bi); \
        (ar) += (br); (ai) += (bi); \
        (br) = _tr * (wr) - _ti * (wi); \
        (bi) = _tr * (wi) + _ti * (wr); }

    #pragma unroll
    for (int p = 0; p < 2; ++p) {
        #pragma unroll
        for (int q = 0; q < 8; ++q) CBFLY(zr[p][q], zi[p][q], zr[p][q+8], zi[p][q+8], W16R[q], W16I[q]);
        #pragma unroll
        for (int g = 0; g < 16; g += 8)
            #pragma unroll
            for (int q = 0; q < 4; ++q) CBFLY(zr[p][g+q], zi[p][g+q], zr[p][g+q+4], zi[p][g+q+4], W16R[2*q], W16I[2*q]);
        #pragma unroll
        for (int g = 0; g < 16; g += 4)
            #pragma unroll
            for (int q = 0; q < 2; ++q) CBFLY(zr[p][g+q], zi[p][g+q], zr[p][g+q+2], zi[p][g+q+2], W16R[4*q], W16I[4*q]);
        #pragma unroll
        for (int g = 0; g < 16; g += 2) CBFLY(zr[p][g], zi[p][g], zr[p][g+1], zi[p][g+1], 1.0f, 0.0f);
    }

    // ---- B) cross twiddle ----
    #pragma unroll
    for (int r = 1; r < 16; ++r) {
        const float c1 = wkr[BREV4[r]];
        const float s1 = wki[BREV4[r]];
        #pragma unroll
        for (int p = 0; p < 2; ++p) {
            const float xr = zr[p][r], xi = zi[p][r];
            zr[p][r] = xr * c1 - xi * s1;
            zi[p][r] = xr * s1 + xi * c1;
        }
    }

    // ---- C) 64-pt DIF FFT across lanes ----
    {
        cstage_sum(zr, zi, (lane & 32) ? -2.0f : 0.0f, c64[0], s64[0],
                   [](float v) { return plsum32(v); });
        cstage_sum(zr, zi, (lane & 16) ? -2.0f : 0.0f, c64[1], s64[1],
                   [](float v) { return plsum16(v); });
        float sg;
        sg = (lane & 8) ? -1.0f : 1.0f;
        cstage(zr, zi, sg, c64[2], s64[2], [](float v) { return dppf<DPP_XOR8>(v); });
        sg = (lane & 4) ? -1.0f : 1.0f;
        cstage(zr, zi, sg, c64[3], s64[3], [](float v) { return __shfl_xor(v, 4); });
        sg = (lane & 2) ? -1.0f : 1.0f;
        cstage(zr, zi, sg, c64[4], s64[4], [](float v) { return dppf<DPP_XOR2>(v); });
        sg = (lane & 1) ? -1.0f : 1.0f;
        cstage(zr, zi, sg, c64[5], s64[5], [](float v) { return dppf<DPP_XOR1>(v); });
    }

    // ---- separation + magnitude -> packed bf16x4 smag (work split across lane pair) ----
    // Hi lane computes from its reg SIG[r] (bin 1024-klo, mirror of klo); partner
    // operand from lo lane's reg r. Each lane sends what its partner needs:
    // lo sends z1[r], hi sends z0[SIG[r]]. Bitwise equal to the full computation.
    const int k2 = (int)(__brev((unsigned)lane) >> 26);
    const int lp0 = (int)(__brev((unsigned)((64 - k2) & 63)) >> 26);
    const bool hasbin = (k2 < 32);
    #pragma unroll
    for (int r = 1; r < 16; ++r) {
        const float sxr = hasbin ? zr[1][r] : zr[0][SIG[r]];
        const float sxi = hasbin ? zi[1][r] : zi[0][SIG[r]];
        const float cx = __shfl_xor(sxr, 63);
        const float cy = __shfl_xor(sxi, 63);
        const float a = hasbin ? zr[0][r] : zr[1][SIG[r]];
        const float b = hasbin ? zi[0][r] : zi[1][SIG[r]];
        const float sA = a + cx, dA = b - cy;
        const float sB = b + cy, dB = a - cx;
        const float magA = sqrtf(sA * sA + dA * dA);
        const float magB = sqrtf(sB * sB + dB * dB);
        const unsigned pk = cvt_pk_bf16(magA, magB);
        const unsigned pko = (unsigned)__shfl_xor((int)pk, 63);
        if (hasbin) {
            const int k1 = BREV4[r];
            const int k = k2 * 16 + k1;
            smag4[w][(k & ~15) | (k1 ^ (k2 & 15))] = make_uint2(pk, pko);
        }
    }
    {   // r == 0: bins are multiples of 16; partner via lp0 broadcast
        const float cx0 = __shfl(zr[0][0], lp0), cy0 = __shfl(zi[0][0], lp0);
        const float cx1 = __shfl(zr[1][0], lp0), cy1 = __shfl(zi[1][0], lp0);
        if (hasbin) {
            const float a0 = zr[0][0], b0 = zi[0][0];
            const float mA0 = sqrtf((a0 + cx0) * (a0 + cx0) + (b0 - cy0) * (b0 - cy0));
            const float mB0 = sqrtf((b0 + cy0) * (b0 + cy0) + (a0 - cx0) * (a0 - cx0));
            const float a1 = zr[1][0], b1 = zi[1][0];
            const float mA1 = sqrtf((a1 + cx1) * (a1 + cx1) + (b1 - cy1) * (b1 - cy1));
            const float mB1 = sqrtf((b1 + cy1) * (b1 + cy1) + (a1 - cx1) * (a1 - cx1));
            const int k = k2 * 16;
            smag4[w][(k & ~15) | (0 ^ (k2 & 15))] =
                make_uint2(cvt_pk_bf16(mA0, mB0), cvt_pk_bf16(mA1, mB1));
        }
    }

    // ---- mel: 160 tasks = (m, half-triangle), 4 frames/task, split up/down loops ----
    #pragma unroll
    for (int ii = 0; ii < 3; ++ii) {
        const int t2 = lane + 64 * ii;
        if (t2 < 2 * N_MELS) {
            const int m = 79 - (t2 >> 1);      // descending width order
            const int half = t2 & 1;
            const int ka = ks_l[m], kb = ks_l[m + 1], kc = ks_l[m + 2];
            const int km = (ka + kc + 1) >> 1;
            const int kbeg = half ? km : ka;
            const int kend = half ? kc : km;
            float a0 = 0.f, b0 = 0.f, a1 = 0.f, b1 = 0.f;
            const int upend = min(kb, kend);
            for (int k = kbeg; k < upend; ++k) {
                const int sl = swz(k);
                const uint2 mg = smag4[w][sl];
                const float ws = swu[sl];
                a0 = fmaf(lo16f(mg.x), ws, a0);
                b0 = fmaf(hi16f(mg.x), ws, b0);
                a1 = fmaf(lo16f(mg.y), ws, a1);
                b1 = fmaf(hi16f(mg.y), ws, b1);
            }
            const int dnbeg = max(kb, kbeg);
            for (int k = dnbeg; k < kend; ++k) {
                const int sl = swz(k);
                const uint2 mg = smag4[w][sl];
                const float ws = swd[sl];
                a0 = fmaf(lo16f(mg.x), ws, a0);
                b0 = fmaf(hi16f(mg.x), ws, b0);
                a1 = fmaf(lo16f(mg.y), ws, a1);
                b1 = fmaf(hi16f(mg.y), ws, b1);
            }
            a0 += dppf<DPP_XOR1>(a0);  b0 += dppf<DPP_XOR1>(b0);
            a1 += dppf<DPP_XOR1>(a1);  b1 += dppf<DPP_XOR1>(b1);
            const float v0 = half ? b0 : a0;
            const float v1 = half ? b1 : a1;
            const unsigned gA = (unsigned)(g0 + half);
            const unsigned bbA = gA / NUM_FRAMES;
            const unsigned ffA = gA - bbA * NUM_FRAMES;
            out[((size_t)bbA * N_MELS + m) * NUM_FRAMES + ffA] = v0;
            const unsigned gB = (unsigned)(g0 + 2 + half);
            const unsigned bbB = gB / NUM_FRAMES;
            const unsigned ffB = gB - bbB * NUM_FRAMES;
            out[((size_t)bbB * N_MELS + m) * NUM_FRAMES + ffB] = v1;
        }
    }
}

extern "C" void kernel_launch(void* const* d_in, const int* in_sizes, int n_in,
                              void* d_out, int out_size, void* d_ws, size_t ws_size,
                              hipStream_t stream) {
    const float* wav    = (const float*)d_in[0];
    const float* window = (const float*)d_in[1];
    const float* fb     = (const float*)d_in[2];
    const float* cosT   = (const float*)d_in[3];
    const float* sinT   = (const float*)d_in[4];
    float* out = (float*)d_out;

    const int blocks = TOTAL_FRAMES / 16;  // 1251: 4 waves/block, 4 frames/wave
    melspec_pk7_kernel<<<blocks, 256, 0, stream>>>(wav, window, fb, cosT, sinT, out);
}